// Round 1
// baseline (1463.098 us; speedup 1.0000x reference)
//
#include <hip/hip_runtime.h>
#include <hip/hip_bf16.h>
#include <cstdint>
#include <cstddef>

// Problem constants
#define BATCH   8192
#define DIM     768
#define NTOT    6291456      // BATCH*DIM
#define NHALF   3145728
#define NLAYERS 4

// ---------------------------------------------------------------------------
// Threefry-2x32 (matches jax/_src/prng.py exactly; 20 rounds, 5 key injections)
// ---------------------------------------------------------------------------
__host__ __device__ __forceinline__ uint32_t rotl32(uint32_t v, int d) {
  return (v << d) | (v >> (32 - d));
}

__host__ __device__ __forceinline__ void threefry2x32(
    uint32_t k0, uint32_t k1, uint32_t x0, uint32_t x1,
    uint32_t& o0, uint32_t& o1) {
  uint32_t ks2 = k0 ^ k1 ^ 0x1BD11BDAu;
  x0 += k0; x1 += k1;
#define TF_R(r) { x0 += x1; x1 = rotl32(x1, (r)) ^ x0; }
  TF_R(13) TF_R(15) TF_R(26) TF_R(6)
  x0 += k1; x1 += ks2 + 1u;
  TF_R(17) TF_R(29) TF_R(16) TF_R(24)
  x0 += ks2; x1 += k0 + 2u;
  TF_R(13) TF_R(15) TF_R(26) TF_R(6)
  x0 += k0; x1 += k1 + 3u;
  TF_R(17) TF_R(29) TF_R(16) TF_R(24)
  x0 += k1; x1 += ks2 + 4u;
  TF_R(13) TF_R(15) TF_R(26) TF_R(6)
  x0 += ks2; x1 += k0 + 5u;
#undef TF_R
  o0 = x0; o1 = x1;
}

__device__ __forceinline__ double sigmoid_d(double x) {
  return 1.0 / (1.0 + exp(-x));
}

// ---------------------------------------------------------------------------
// Kernel 1: embedding gather -> x_d and x_s (identical initial x)
// x[b, f]: f in [0,384) from first halves of E0/E1/E2, [384,768) second halves
// ---------------------------------------------------------------------------
__global__ __launch_bounds__(256) void gather_kernel(
    const int* __restrict__ x_p, const int* __restrict__ x_a,
    const int* __restrict__ x_c,
    const float* __restrict__ E0, const float* __restrict__ E1,
    const float* __restrict__ E2,
    float* __restrict__ xd, float* __restrict__ xs) {
  int j = blockIdx.x * 256 + threadIdx.x;      // 0 .. NTOT-1
  int b = j / DIM;
  int f = j - b * DIM;
  int half = f / 384;          // 0 or 1
  int w = f - half * 384;      // 0..383
  int t = w >> 7;              // table 0..2
  int c = (w & 127) + (half << 7);
  int idx;
  const float* E;
  if (t == 0)      { E = E0; idx = x_p[b]; }
  else if (t == 1) { E = E1; idx = x_a[b]; }
  else             { E = E2; idx = x_c[b]; }
  float v = E[(size_t)idx * 256 + c];
  xd[j] = v;
  xs[j] = v;
}

// ---------------------------------------------------------------------------
// Kernel 2: fp32 GEMM  cross = x @ W[l]^T + b[l]  for both nets (blockIdx.z)
// A [8192x768] row-major, W row [768x768] row-major (NT gemm: dot of rows).
// 128x128 tile, BK=16, 256 threads, 8x8 microtile, wave-quadrant layout.
// Epilogue: bias add, store cross, fp64 per-block (sum, sumsq) partials.
// ---------------------------------------------------------------------------
__global__ __launch_bounds__(256) void gemm_cross_kernel(
    const float* __restrict__ xd, const float* __restrict__ xs,
    const float* __restrict__ Wd, const float* __restrict__ Ws,
    const float* __restrict__ bd, const float* __restrict__ bs,
    float* __restrict__ crd, float* __restrict__ crs,
    double* __restrict__ partials, int layer) {
  const int net = blockIdx.z;
  const float* A    = net ? xs : xd;
  const float* W    = (net ? Ws : Wd) + (size_t)layer * DIM * DIM;
  const float* bias = (net ? bs : bd) + layer * DIM;
  float* C          = net ? crs : crd;

  __shared__ float As[16][132];   // [k][m], pad 4 -> 16B-aligned k-rows
  __shared__ float Bs[16][132];   // [k][n]

  const int tid = threadIdx.x;
  const int m0 = blockIdx.y * 128;
  const int n0 = blockIdx.x * 128;

  // global->LDS load mapping: 8 floats per thread per tile (2x float4)
  const int lr = tid >> 2;            // 0..63 (row within tile)
  const int lk = (tid & 3) * 4;       // 0,4,8,12 (k offset)

  // compute mapping: 4 waves = 2x2 quadrants of 64x64; 8x8 lanes inside
  const int wave = tid >> 6;
  const int lane = tid & 63;
  const int qr = (wave >> 1) * 64;
  const int qc = (wave & 1) * 64;
  const int rowBase = qr + (lane >> 3) * 8;   // 0..120
  const int colBase = qc + (lane & 7) * 8;    // 0..120

  float acc[8][8];
#pragma unroll
  for (int i = 0; i < 8; ++i)
#pragma unroll
    for (int j = 0; j < 8; ++j) acc[i][j] = 0.0f;

  const float* Arow = A + (size_t)m0 * DIM;
  const float* Brow = W + (size_t)n0 * DIM;

  for (int k0 = 0; k0 < DIM; k0 += 16) {
    float4 a0 = *(const float4*)(Arow + (size_t)lr * DIM + k0 + lk);
    float4 a1 = *(const float4*)(Arow + (size_t)(lr + 64) * DIM + k0 + lk);
    float4 b0 = *(const float4*)(Brow + (size_t)lr * DIM + k0 + lk);
    float4 b1 = *(const float4*)(Brow + (size_t)(lr + 64) * DIM + k0 + lk);
    __syncthreads();
    As[lk + 0][lr] = a0.x; As[lk + 1][lr] = a0.y;
    As[lk + 2][lr] = a0.z; As[lk + 3][lr] = a0.w;
    As[lk + 0][lr + 64] = a1.x; As[lk + 1][lr + 64] = a1.y;
    As[lk + 2][lr + 64] = a1.z; As[lk + 3][lr + 64] = a1.w;
    Bs[lk + 0][lr] = b0.x; Bs[lk + 1][lr] = b0.y;
    Bs[lk + 2][lr] = b0.z; Bs[lk + 3][lr] = b0.w;
    Bs[lk + 0][lr + 64] = b1.x; Bs[lk + 1][lr + 64] = b1.y;
    Bs[lk + 2][lr + 64] = b1.z; Bs[lk + 3][lr + 64] = b1.w;
    __syncthreads();
#pragma unroll
    for (int k = 0; k < 16; ++k) {
      float a[8], b[8];
      *(float4*)&a[0] = *(const float4*)&As[k][rowBase];
      *(float4*)&a[4] = *(const float4*)&As[k][rowBase + 4];
      *(float4*)&b[0] = *(const float4*)&Bs[k][colBase];
      *(float4*)&b[4] = *(const float4*)&Bs[k][colBase + 4];
#pragma unroll
      for (int i = 0; i < 8; ++i)
#pragma unroll
        for (int j = 0; j < 8; ++j)
          acc[i][j] = fmaf(a[i], b[j], acc[i][j]);
    }
  }

  // epilogue: bias, store, fp64 sum/sumsq
  float breg[8];
  *(float4*)&breg[0] = *(const float4*)(bias + n0 + colBase);
  *(float4*)&breg[4] = *(const float4*)(bias + n0 + colBase + 4);
  double s = 0.0, q = 0.0;
#pragma unroll
  for (int i = 0; i < 8; ++i) {
    size_t row = (size_t)(m0 + rowBase + i);
    float tmp[8];
#pragma unroll
    for (int j = 0; j < 8; ++j) {
      float c = acc[i][j] + breg[j];
      tmp[j] = c;
      s += (double)c;
      q += (double)c * (double)c;
    }
    *(float4*)(C + row * DIM + n0 + colBase)     = *(float4*)&tmp[0];
    *(float4*)(C + row * DIM + n0 + colBase + 4) = *(float4*)&tmp[4];
  }
#pragma unroll
  for (int off = 32; off > 0; off >>= 1) {
    s += __shfl_down(s, off);
    q += __shfl_down(q, off);
  }
  __shared__ double red[4][2];
  if (lane == 0) { red[wave][0] = s; red[wave][1] = q; }
  __syncthreads();
  if (tid == 0) {
    double S = red[0][0] + red[1][0] + red[2][0] + red[3][0];
    double Q = red[0][1] + red[1][1] + red[2][1] + red[3][1];
    int bid = blockIdx.y * gridDim.x + blockIdx.x;   // 0..383
    partials[((size_t)net * 384 + bid) * 2 + 0] = S;
    partials[((size_t)net * 384 + bid) * 2 + 1] = Q;
  }
}

// ---------------------------------------------------------------------------
// Kernel 3: reduce 384 per-block partials -> stats[net] = {sum, sumsq}
// ---------------------------------------------------------------------------
__global__ __launch_bounds__(256) void finalize_stats_kernel(
    const double* __restrict__ partials, double* __restrict__ stats) {
  int net = blockIdx.x;
  const double* P = partials + (size_t)net * 384 * 2;
  int tid = threadIdx.x;
  double s = 0.0, q = 0.0;
  for (int i = tid; i < 384; i += 256) {
    s += P[i * 2 + 0];
    q += P[i * 2 + 1];
  }
#pragma unroll
  for (int off = 32; off > 0; off >>= 1) {
    s += __shfl_down(s, off);
    q += __shfl_down(q, off);
  }
  __shared__ double red[4][2];
  int wave = tid >> 6, lane = tid & 63;
  if (lane == 0) { red[wave][0] = s; red[wave][1] = q; }
  __syncthreads();
  if (tid == 0) {
    stats[net * 2 + 0] = red[0][0] + red[1][0] + red[2][0] + red[3][0];
    stats[net * 2 + 1] = red[0][1] + red[1][1] + red[2][1] + red[3][1];
  }
}

// ---------------------------------------------------------------------------
// Kernel 4: full-tensor layernorm -> sigmoid -> threefry bernoulli mask ->
//           x += cross*mask.  One element per thread (partitionable mapping:
//           bits[j] = o0^o1 of threefry(key, hi=0, lo=j)).
// ---------------------------------------------------------------------------
__global__ __launch_bounds__(256) void mask_update_kernel(
    float* __restrict__ xd, float* __restrict__ xs,
    const float* __restrict__ crd, const float* __restrict__ crs,
    const double* __restrict__ stats,
    uint32_t kd0, uint32_t kd1, uint32_t ks0, uint32_t ks1) {
  const int net = blockIdx.y;
  float* x = net ? xs : xd;
  const float* cr = net ? crs : crd;
  const uint32_t k0 = net ? ks0 : kd0;
  const uint32_t k1 = net ? ks1 : kd1;

  const double invN = 1.0 / (double)NTOT;
  double meand = stats[net * 2 + 0] * invN;
  double vard  = stats[net * 2 + 1] * invN - meand * meand;
  float m  = (float)meand;
  float v  = (float)vard;
  float sv = v + 1e-5f;                          // ref: v + EPS in fp32
  float rs = (float)(1.0 / sqrt((double)sv));    // ~correctly-rounded rsqrt

  uint32_t j = blockIdx.x * 256u + threadIdx.x;  // 0..NTOT-1
  float c = cr[j];
  float ln = (c - m) * rs;                       // fp32, as reference
  float p = (float)sigmoid_d((double)ln);        // fp32-rounded sigmoid
  uint32_t o0, o1;
  threefry2x32(k0, k1, 0u, j, o0, o1);
  uint32_t bits = o0 ^ o1;
  float u = __uint_as_float(0x3F800000u | (bits >> 9)) - 1.0f;
  if (u < p) x[j] = x[j] + c;
}

// ---------------------------------------------------------------------------
// Kernel 5: heads. One wave per row: 4 dot products (x_d,x_s) x (wfd,wfs),
// sigmoids, y_pred_d -> out, per-block fp64 BCE partials.
// ---------------------------------------------------------------------------
__global__ __launch_bounds__(256) void head_kernel(
    const float* __restrict__ xd, const float* __restrict__ xs,
    const float* __restrict__ wfd, const float* __restrict__ wfs,
    const float* __restrict__ bfd_p, const float* __restrict__ bfs_p,
    const float* __restrict__ y_true,
    float* __restrict__ out, double* __restrict__ bce_part) {
  const int wave = threadIdx.x >> 6;
  const int lane = threadIdx.x & 63;
  const int row = blockIdx.x * 4 + wave;
  const float* xdr = xd + (size_t)row * DIM;
  const float* xsr = xs + (size_t)row * DIM;

  float dd = 0.f, dsw = 0.f, sd = 0.f, ssw = 0.f;
  for (int t = lane; t < DIM; t += 64) {
    float vd = xdr[t], vs = xsr[t];
    float wd = wfd[t], ws = wfs[t];
    dd  = fmaf(vd, wd, dd);
    dsw = fmaf(vd, ws, dsw);
    sd  = fmaf(vs, wd, sd);
    ssw = fmaf(vs, ws, ssw);
  }
#pragma unroll
  for (int off = 32; off > 0; off >>= 1) {
    dd  += __shfl_down(dd, off);
    dsw += __shfl_down(dsw, off);
    sd  += __shfl_down(sd, off);
    ssw += __shfl_down(ssw, off);
  }
  __shared__ double redd[4], reds[4];
  if (lane == 0) {
    float bfd = *bfd_p, bfs = *bfs_p;
    double sdd = sigmoid_d((double)(dd + bfd));    // fc_d(x_d)
    double ssd = sigmoid_d((double)(dsw + bfs));   // fc_s(x_d)
    double sds = sigmoid_d((double)(sd + bfd));    // fc_d(x_s)
    double sss = sigmoid_d((double)(ssw + bfs));   // fc_s(x_s)
    double ypd = 0.5 * (sdd + sss);
    double yps = 0.5 * (sds + ssd);
    out[row] = (float)ypd;
    double y = (double)y_true[row];
    redd[wave] = -(y * log(ypd) + (1.0 - y) * log(1.0 - ypd));
    reds[wave] = -(y * log(yps) + (1.0 - y) * log(1.0 - yps));
  }
  __syncthreads();
  if (threadIdx.x == 0) {
    bce_part[(size_t)blockIdx.x * 2 + 0] = redd[0] + redd[1] + redd[2] + redd[3];
    bce_part[(size_t)blockIdx.x * 2 + 1] = reds[0] + reds[1] + reds[2] + reds[3];
  }
}

// ---------------------------------------------------------------------------
// Kernel 6: reduce BCE partials -> tri_loss
// ---------------------------------------------------------------------------
__global__ __launch_bounds__(256) void loss_kernel(
    const double* __restrict__ bce_part, float* __restrict__ out_tri) {
  int tid = threadIdx.x;
  double sdl = 0.0, ssl = 0.0;
  for (int i = tid; i < 2048; i += 256) {
    sdl += bce_part[i * 2 + 0];
    ssl += bce_part[i * 2 + 1];
  }
#pragma unroll
  for (int off = 32; off > 0; off >>= 1) {
    sdl += __shfl_down(sdl, off);
    ssl += __shfl_down(ssl, off);
  }
  __shared__ double red[4][2];
  int wave = tid >> 6, lane = tid & 63;
  if (lane == 0) { red[wave][0] = sdl; red[wave][1] = ssl; }
  __syncthreads();
  if (tid == 0) {
    double loss_d = (red[0][0] + red[1][0] + red[2][0] + red[3][0]) / (double)BATCH;
    double loss_s = (red[0][1] + red[1][1] + red[2][1] + red[3][1]) / (double)BATCH;
    double bce = loss_d + loss_s;
    double wd = fmax(0.0, loss_d - bce);
    double ws = fmax(0.0, loss_s - bce);
    out_tri[0] = (float)(bce + wd * loss_d + ws * loss_s);
  }
}

// ---------------------------------------------------------------------------
// Launch
// ---------------------------------------------------------------------------
extern "C" void kernel_launch(void* const* d_in, const int* in_sizes, int n_in,
                              void* d_out, int out_size, void* d_ws, size_t ws_size,
                              hipStream_t stream) {
  const int* x_p = (const int*)d_in[0];
  const int* x_a = (const int*)d_in[1];
  const int* x_c = (const int*)d_in[2];
  const float* y_true = (const float*)d_in[3];
  const float* E0 = (const float*)d_in[4];
  const float* E1 = (const float*)d_in[5];
  const float* E2 = (const float*)d_in[6];
  const float* Wd = (const float*)d_in[7];
  const float* bd = (const float*)d_in[8];
  const float* Ws = (const float*)d_in[9];
  const float* bs = (const float*)d_in[10];
  const float* wfd = (const float*)d_in[11];
  const float* bfd = (const float*)d_in[12];
  const float* wfs = (const float*)d_in[13];
  const float* bfs = (const float*)d_in[14];
  float* out = (float*)d_out;

  // workspace layout
  float* xd  = (float*)d_ws;
  float* xs  = xd + NTOT;
  float* crd = xs + NTOT;
  float* crs = crd + NTOT;
  double* partials = (double*)(crs + NTOT);    // 2*384*2 doubles
  double* stats    = partials + 2 * 384 * 2;   // 4 doubles
  double* bce_part = stats + 4;                // 2048*2 doubles

  gather_kernel<<<NTOT / 256, 256, 0, stream>>>(x_p, x_a, x_c, E0, E1, E2, xd, xs);

  for (int l = 0; l < NLAYERS; ++l) {
    gemm_cross_kernel<<<dim3(6, 64, 2), 256, 0, stream>>>(
        xd, xs, Wd, Ws, bd, bs, crd, crs, partials, l);
    finalize_stats_kernel<<<2, 256, 0, stream>>>(partials, stats);
    // fold_in(key(42), net*4+l): threefry2x32([0,42], [0, data])
    uint32_t kd0, kd1, ks0, ks1;
    threefry2x32(0u, 42u, 0u, (uint32_t)l, kd0, kd1);
    threefry2x32(0u, 42u, 0u, (uint32_t)(4 + l), ks0, ks1);
    mask_update_kernel<<<dim3(NTOT / 256, 2), 256, 0, stream>>>(
        xd, xs, crd, crs, stats, kd0, kd1, ks0, ks1);
  }

  head_kernel<<<BATCH / 4, 256, 0, stream>>>(
      xd, xs, wfd, wfs, bfd, bfs, y_true, out, bce_part);
  loss_kernel<<<1, 256, 0, stream>>>(bce_part, out + BATCH);
}